// Round 1
// baseline (76.502 us; speedup 1.0000x reference)
//
#include <hip/hip_runtime.h>

#define H 224
#define W 224
#define HOUT 112
#define P 12544      // 112*112
#define PPAD 13312   // 13*1024
#define ITILES 13
#define ITILE 1024
#define JCHUNK 256
#define JCHUNKS 49   // 49*256 = 12544 exactly
#define REC 8        // floats per pixel record

__device__ __forceinline__ float fast_exp2(float x) {
    return __builtin_amdgcn_exp2f(x);
}

// Per-pixel record: [fx, fy, fz, A, u, 2u-1, 1-u, 0]
//   f = rgb/15 (nearest-downsampled), A = -0.5*log2(e)*|f|^2
//   u = 2x2-mean of softmax channel-0 (bilinear downsample of softmax)
__global__ __launch_bounds__(256) void crf_prep(const float* __restrict__ fcams,
                                                const float* __restrict__ img,
                                                float* __restrict__ rec) {
    int idx = blockIdx.x * 256 + threadIdx.x;   // [0, 2*PPAD)
    int b = idx / PPAD;
    int p = idx - b * PPAD;
    float fx = 0.f, fy = 0.f, fz = 0.f, A = -1e30f, u = 0.f, pw = 0.f, qw = 0.f;
    if (p < P) {
        int y = p / HOUT, x = p - y * HOUT;
        const float* ib = img + (size_t)b * 3 * H * W;
        int off = (2 * y) * W + 2 * x;
        const float inv_sigma = 1.0f / 15.0f;
        fx = ib[off] * inv_sigma;
        fy = ib[H * W + off] * inv_sigma;
        fz = ib[2 * H * W + off] * inv_sigma;
        const float c0 = -0.72134752044448170f;   // -0.5*log2(e)
        A = c0 * (fx * fx + fy * fy + fz * fz);
        const float* cb = fcams + (size_t)b * 2 * H * W;
        const float l2e = 1.44269504088896340f;
        float s = 0.f;
        #pragma unroll
        for (int dy = 0; dy < 2; ++dy) {
            #pragma unroll
            for (int dx = 0; dx < 2; ++dx) {
                int o = (2 * y + dy) * W + (2 * x + dx);
                float d = cb[o] - cb[H * W + o];           // a0 - a1
                s += 1.0f / (1.0f + fast_exp2(-d * l2e));  // sigmoid = softmax ch0
            }
        }
        u = 0.25f * s;
        pw = 2.f * u - 1.f;
        qw = 1.f - u;
    }
    float* r = rec + (size_t)idx * REC;
    r[0] = fx; r[1] = fy; r[2] = fz; r[3] = A;
    r[4] = u;  r[5] = pw; r[6] = qw; r[7] = 0.f;
}

// E = sum_{i,j} 2^(A_i + A_j + log2e * f_i.f_j) * (u_j*(2u_i-1) + (1-u_i))
__global__ __launch_bounds__(256) void crf_energy(const float* __restrict__ rec,
                                                  float* __restrict__ out) {
    __shared__ float4 js[JCHUNK * 2];
    int bid = blockIdx.x;
    int b   = bid / (ITILES * JCHUNKS);
    int r   = bid - b * (ITILES * JCHUNKS);
    int it  = r / JCHUNKS;
    int jc  = r - it * JCHUNKS;
    const float* base = rec + (size_t)b * PPAD * REC;

    // stage the j-chunk (256 records = 8 KB) into LDS
    const float4* src = (const float4*)(base + (size_t)jc * JCHUNK * REC);
    for (int k = threadIdx.x; k < JCHUNK * 2; k += 256) js[k] = src[k];

    // load this thread's 4 i-pixels
    const float m2c = 1.44269504088896340f;   // log2(e) = -2 * (-0.5*log2 e)
    float fx2[4], fy2[4], fz2[4], Ai[4], pi[4], qi[4];
    int i0 = it * ITILE + threadIdx.x * 4;
    #pragma unroll
    for (int k = 0; k < 4; ++k) {
        const float4* rp = (const float4*)(base + (size_t)(i0 + k) * REC);
        float4 r0 = rp[0];
        float4 r1 = rp[1];
        fx2[k] = r0.x * m2c; fy2[k] = r0.y * m2c; fz2[k] = r0.z * m2c;
        Ai[k] = r0.w; pi[k] = r1.y; qi[k] = r1.z;
    }
    __syncthreads();

    float acc[4] = {0.f, 0.f, 0.f, 0.f};
    #pragma unroll 4
    for (int j = 0; j < JCHUNK; ++j) {
        float4 r0 = js[2 * j];       // fx, fy, fz, Aj  (wave-uniform broadcast)
        float4 r1 = js[2 * j + 1];   // u, pw, qw, pad
        float Aj = r0.w, uj = r1.x;
        #pragma unroll
        for (int k = 0; k < 4; ++k) {
            float t = Ai[k] + Aj;
            t = fmaf(fx2[k], r0.x, t);
            t = fmaf(fy2[k], r0.y, t);
            t = fmaf(fz2[k], r0.z, t);
            float kx = fast_exp2(t);
            float w  = fmaf(pi[k], uj, qi[k]);
            acc[k] = fmaf(kx, w, acc[k]);
        }
    }
    float tot = (acc[0] + acc[1]) + (acc[2] + acc[3]);
    #pragma unroll
    for (int o = 32; o > 0; o >>= 1) tot += __shfl_down(tot, o);

    __shared__ float wsum[4];
    int lane = threadIdx.x & 63, wid = threadIdx.x >> 6;
    if (lane == 0) wsum[wid] = tot;
    __syncthreads();
    if (threadIdx.x == 0) {
        atomicAdd(out, -0.5f * ((wsum[0] + wsum[1]) + (wsum[2] + wsum[3])));
    }
}

extern "C" void kernel_launch(void* const* d_in, const int* in_sizes, int n_in,
                              void* d_out, int out_size, void* d_ws, size_t ws_size,
                              hipStream_t stream) {
    const float* fcams = (const float*)d_in[0];   // [2, 2, 224, 224]
    const float* img   = (const float*)d_in[1];   // [2, 3, 224, 224]
    float* out = (float*)d_out;                   // scalar
    float* rec = (float*)d_ws;                    // 2 * PPAD * 8 floats = 832 KB

    hipMemsetAsync(d_out, 0, sizeof(float), stream);
    crf_prep<<<(2 * PPAD) / 256, 256, 0, stream>>>(fcams, img, rec);
    crf_energy<<<2 * ITILES * JCHUNKS, 256, 0, stream>>>(rec, out);
}

// Round 2
// 51.464 us; speedup vs baseline: 1.4865x; 1.4865x over previous
//
#include <hip/hip_runtime.h>

#define H 224
#define W 224
#define HOUT 112
#define P 12544        // 112*112 real pixels per batch
#define PPAD 13312     // 13*1024 (i-side padded)
#define NTILES 13      // i-tiles of 1024
#define ITILE 1024
#define JCHUNK 64
#define NCHUNKS 196    // real j-chunks: 196*64 = 12544
#define JOBS_PER_BATCH 1300

__device__ __forceinline__ float fast_exp2(float x) {
    return __builtin_amdgcn_exp2f(x);
}

// Per-pixel records:
//   recA[p] = (fx, fy, fz, A)  with f = rgb/15 (nearest-down), A = -0.5*log2e*|f|^2
//   recU[p] = u = 2x2-mean of softmax channel-0
__global__ __launch_bounds__(256) void crf_prep(const float* __restrict__ fcams,
                                                const float* __restrict__ img,
                                                float4* __restrict__ recA,
                                                float* __restrict__ recU) {
    int idx = blockIdx.x * 256 + threadIdx.x;   // [0, 2*PPAD)
    int b = idx / PPAD;
    int p = idx - b * PPAD;
    float fx = 0.f, fy = 0.f, fz = 0.f, A = -1e30f, u = 0.f;
    if (p < P) {
        int y = p / HOUT, x = p - y * HOUT;
        const float* ib = img + (size_t)b * 3 * H * W;
        int off = (2 * y) * W + 2 * x;
        const float inv_sigma = 1.0f / 15.0f;
        fx = ib[off] * inv_sigma;
        fy = ib[H * W + off] * inv_sigma;
        fz = ib[2 * H * W + off] * inv_sigma;
        const float c0 = -0.72134752044448170f;   // -0.5*log2(e)
        A = c0 * (fx * fx + fy * fy + fz * fz);
        const float* cb = fcams + (size_t)b * 2 * H * W;
        const float l2e = 1.44269504088896340f;
        float s = 0.f;
        #pragma unroll
        for (int dy = 0; dy < 2; ++dy) {
            #pragma unroll
            for (int dx = 0; dx < 2; ++dx) {
                int o = (2 * y + dy) * W + (2 * x + dx);
                float d = cb[o] - cb[H * W + o];           // a0 - a1
                s += 1.0f / (1.0f + fast_exp2(-d * l2e));  // sigmoid = softmax ch0
            }
        }
        u = 0.25f * s;
    }
    recA[idx] = make_float4(fx, fy, fz, A);
    recU[idx] = u;
}

// Triangular-tiled energy:
//   per i: S_u = sum_j K_ij * u_j, S_1 = sum_j K_ij
//   ordered job contribution  = p_i*S_u + q_i*S_1            (scale 1)
//   symmetric job (both dirs) = 2*(p_i*S_u + q_i*S_1)        (scale 2)
__global__ __launch_bounds__(256) void crf_energy(const float4* __restrict__ recA,
                                                  const float* __restrict__ recU,
                                                  float* __restrict__ out) {
    __shared__ float4 jsA[JCHUNK];
    __shared__ float  jsU[JCHUNK];

    int bid = blockIdx.x;
    int b = bid / JOBS_PER_BATCH;
    int r = bid - b * JOBS_PER_BATCH;
    // decode (it, jc): tile it has jobs jc in [16*it, ...]; it<12: 16 ordered + (180-16*it) symmetric
    int it = 0;
    #pragma unroll 1
    for (; it < NTILES; ++it) {
        int cnt = (it < 12) ? (NCHUNKS - 16 * it) : 4;
        if (r < cnt) break;
        r -= cnt;
    }
    int jc = 16 * it + r;
    float scale = (r >= 16) ? 2.0f : 1.0f;

    const float4* baseA = recA + (size_t)b * PPAD;
    const float*  baseU = recU + (size_t)b * PPAD;

    // stage the j-chunk (64 records)
    if (threadIdx.x < JCHUNK) {
        jsA[threadIdx.x] = baseA[jc * JCHUNK + threadIdx.x];
        jsU[threadIdx.x] = baseU[jc * JCHUNK + threadIdx.x];
    }

    // this thread's 4 i-pixels
    const float l2e = 1.44269504088896340f;
    float fx2[4], fy2[4], fz2[4], Ai[4], pi[4], qi[4];
    int i0 = it * ITILE + threadIdx.x * 4;
    #pragma unroll
    for (int k = 0; k < 4; ++k) {
        float4 a = baseA[i0 + k];
        float  u = baseU[i0 + k];
        fx2[k] = a.x * l2e; fy2[k] = a.y * l2e; fz2[k] = a.z * l2e;
        Ai[k] = a.w;
        pi[k] = 2.f * u - 1.f;
        qi[k] = 1.f - u;
    }
    __syncthreads();

    float Su[4] = {0.f, 0.f, 0.f, 0.f};
    float S1[4] = {0.f, 0.f, 0.f, 0.f};
    #pragma unroll 4
    for (int j = 0; j < JCHUNK; ++j) {
        float4 a = jsA[j];    // wave-uniform broadcast
        float uj = jsU[j];
        #pragma unroll
        for (int k = 0; k < 4; ++k) {
            float t = Ai[k] + a.w;
            t = fmaf(fx2[k], a.x, t);
            t = fmaf(fy2[k], a.y, t);
            t = fmaf(fz2[k], a.z, t);
            float kx = fast_exp2(t);
            Su[k] = fmaf(kx, uj, Su[k]);
            S1[k] += kx;
        }
    }
    float tot = 0.f;
    #pragma unroll
    for (int k = 0; k < 4; ++k) tot += pi[k] * Su[k] + qi[k] * S1[k];
    tot *= scale;

    #pragma unroll
    for (int o = 32; o > 0; o >>= 1) tot += __shfl_down(tot, o);

    __shared__ float wsum[4];
    int lane = threadIdx.x & 63, wid = threadIdx.x >> 6;
    if (lane == 0) wsum[wid] = tot;
    __syncthreads();
    if (threadIdx.x == 0) {
        atomicAdd(out, -0.5f * ((wsum[0] + wsum[1]) + (wsum[2] + wsum[3])));
    }
}

extern "C" void kernel_launch(void* const* d_in, const int* in_sizes, int n_in,
                              void* d_out, int out_size, void* d_ws, size_t ws_size,
                              hipStream_t stream) {
    const float* fcams = (const float*)d_in[0];   // [2, 2, 224, 224]
    const float* img   = (const float*)d_in[1];   // [2, 3, 224, 224]
    float* out = (float*)d_out;                   // scalar

    float4* recA = (float4*)d_ws;                        // 2*PPAD*16 B = 416 KB
    float*  recU = (float*)((char*)d_ws + 2 * PPAD * sizeof(float4));  // +104 KB

    hipMemsetAsync(d_out, 0, sizeof(float), stream);
    crf_prep<<<(2 * PPAD) / 256, 256, 0, stream>>>(fcams, img, recA, recU);
    crf_energy<<<2 * JOBS_PER_BATCH, 256, 0, stream>>>(recA, recU, out);
}